// Round 2
// baseline (703.942 us; speedup 1.0000x reference)
//
#include <hip/hip_runtime.h>
#include <math.h>

#define Bc 16
#define Nc 4096
#define Cc 256

typedef __attribute__((ext_vector_type(8))) short short8;
typedef __attribute__((ext_vector_type(4))) float floatx4;

__device__ __forceinline__ unsigned short f2bf(float f) {
    union { float f; unsigned int u; } v; v.f = f;
    unsigned int u = v.u;
    return (unsigned short)((u + 0x7fffu + ((u >> 16) & 1u)) >> 16);
}
__device__ __forceinline__ float bf2f(unsigned short u) {
    union { unsigned int u; float f; } v; v.u = ((unsigned int)u) << 16;
    return v.f;
}

// 8-element bf16 fragment loader from either fp32 or bf16 global memory
__device__ __forceinline__ short8 load8(const unsigned short* p) {
    return *(const short8*)p;
}
__device__ __forceinline__ short8 load8(const float* p) {
    const float4 f0 = *(const float4*)(p);
    const float4 f1 = *(const float4*)(p + 4);
    short8 sv;
    sv[0] = (short)f2bf(f0.x); sv[1] = (short)f2bf(f0.y);
    sv[2] = (short)f2bf(f0.z); sv[3] = (short)f2bf(f0.w);
    sv[4] = (short)f2bf(f1.x); sv[5] = (short)f2bf(f1.y);
    sv[6] = (short)f2bf(f1.z); sv[7] = (short)f2bf(f1.w);
    return sv;
}
__device__ __forceinline__ void storeC(float* C, size_t idx, float v) { C[idx] = v; }
__device__ __forceinline__ void storeC(unsigned short* C, size_t idx, float v) { C[idx] = f2bf(v); }

// ---------------------------------------------------------------------------
// GEMM: C[M,N] = concat_K(A0,A1)[M,K] @ W[N,K]^T + bias[N] (+ residual)
// A sources fp32 or bf16; W fp32 (staged to bf16); out fp32 or bf16.
// 128x128 tile, BK=32, 4 waves 2x2, each wave 64x64 via 4x4 mfma 16x16x32 bf16.
// ---------------------------------------------------------------------------
#define BM 128
#define BN 128
#define BK 32

template <typename TA0, typename TA1, typename TOUT>
__global__ __launch_bounds__(256) void gemm_t(
    const TA0* __restrict__ A0, int lda0,
    const TA1* __restrict__ A1, int lda1, int K0,
    const float* __restrict__ W,        // N x K row-major (K contiguous)
    const float* __restrict__ bias,     // N
    const float* __restrict__ residual, // M x N fp32 or null
    TOUT* __restrict__ C,
    int M, int N, int K)
{
    __shared__ alignas(16) unsigned short As[BM * BK];
    __shared__ alignas(16) unsigned short Ws[BN * BK];

    const int t = threadIdx.x;
    const int bm = blockIdx.x, bn = blockIdx.y;
    const int lane = t & 63, wave = t >> 6;
    const int wm = wave >> 1, wn = wave & 1;
    const int quad = lane >> 4, l16 = lane & 15;

    const int seg = t & 3;   // 8-element segment within a 32-wide row
    const int r0 = t >> 2;   // 0..63

    floatx4 acc[4][4];
    #pragma unroll
    for (int i = 0; i < 4; ++i)
        #pragma unroll
        for (int j = 0; j < 4; ++j)
            acc[i][j] = (floatx4){0.f, 0.f, 0.f, 0.f};

    for (int k0 = 0; k0 < K; k0 += BK) {
        #pragma unroll
        for (int half = 0; half < 2; ++half) {
            const int r = r0 + half * 64;
            const size_t grow = (size_t)bm * BM + r;
            const int col = k0 + seg * 8;
            short8 sv;
            if (col < K0) sv = load8(A0 + grow * (size_t)lda0 + col);
            else          sv = load8(A1 + grow * (size_t)lda1 + (col - K0));
            *(short8*)(&As[r * BK + seg * 8]) = sv;
        }
        #pragma unroll
        for (int half = 0; half < 2; ++half) {
            const int r = r0 + half * 64;
            const size_t grow = (size_t)bn * BN + r;
            const int col = k0 + seg * 8;
            *(short8*)(&Ws[r * BK + seg * 8]) = load8(W + grow * (size_t)K + col);
        }
        __syncthreads();

        short8 af[4], wf[4];
        #pragma unroll
        for (int i = 0; i < 4; ++i)
            af[i] = *(const short8*)(&As[(wm * 64 + i * 16 + l16) * BK + quad * 8]);
        #pragma unroll
        for (int i = 0; i < 4; ++i)
            wf[i] = *(const short8*)(&Ws[(wn * 64 + i * 16 + l16) * BK + quad * 8]);
        #pragma unroll
        for (int mi = 0; mi < 4; ++mi)
            #pragma unroll
            for (int ni = 0; ni < 4; ++ni)
                acc[mi][ni] = __builtin_amdgcn_mfma_f32_16x16x32_bf16(
                    af[mi], wf[ni], acc[mi][ni], 0, 0, 0);
        __syncthreads();
    }

    // epilogue: C/D layout col = lane&15, row = quad*4 + reg
    #pragma unroll
    for (int ni = 0; ni < 4; ++ni) {
        const int col = bn * BN + wn * 64 + ni * 16 + l16;
        const float bv = bias[col];
        #pragma unroll
        for (int mi = 0; mi < 4; ++mi) {
            const int rowb = bm * BM + wm * 64 + mi * 16 + quad * 4;
            #pragma unroll
            for (int rg = 0; rg < 4; ++rg) {
                const size_t row = (size_t)rowb + rg;
                float v = acc[mi][ni][rg] + bv;
                if (residual) v += residual[row * (size_t)N + col];
                storeC(C, row * (size_t)N + col, v);
            }
        }
    }
}

// ---------------------------------------------------------------------------
// Fused out-projection weight/bias: Wf = out_proj_w @ tssa_out_w (256x256)
// ---------------------------------------------------------------------------
__global__ __launch_bounds__(256) void wf_kernel(const float* __restrict__ op,
                                                 const float* __restrict__ to,
                                                 float* __restrict__ Wf) {
    const int i = blockIdx.x, j = threadIdx.x;
    float s = 0.f;
    for (int k = 0; k < 256; ++k) s += op[i * 256 + k] * to[k * 256 + j];
    Wf[i * 256 + j] = s;
}

__global__ void bf_kernel(const float* __restrict__ op,
                          const float* __restrict__ tob,
                          const float* __restrict__ opb,
                          float* __restrict__ bf) {
    const int i = threadIdx.x;  // 256
    float s = opb[i];
    for (int k = 0; k < 256; ++k) s += op[i * 256 + k] * tob[k];
    bf[i] = s;
}

// ---------------------------------------------------------------------------
// rope+combine: w_input = ((q+k)*e0 + rot(q+k)*e1 + v)/3, qkv bf16 in, bf16 out
// qkv layout (b, n, h*192 + dd*3 + s)
// ---------------------------------------------------------------------------
__global__ __launch_bounds__(256) void rope_kernel(const unsigned short* __restrict__ qkv,
                                                   const float* __restrict__ enc,
                                                   unsigned short* __restrict__ wi) {
    const size_t tid = (size_t)blockIdx.x * 256 + threadIdx.x;
    const int j = (int)(tid & 31);
    const int h = (int)((tid >> 5) & 3);
    const size_t bn = tid >> 7;            // b*N + n
    const int b = (int)(bn >> 12);
    const int n = (int)(bn & 4095);
    const unsigned short* p = qkv + bn * 768 + h * 192 + j * 6;
    const float q0 = bf2f(p[0]), k0 = bf2f(p[1]), v0 = bf2f(p[2]);
    const float q1 = bf2f(p[3]), k1 = bf2f(p[4]), v1 = bf2f(p[5]);
    const size_t eb = ((size_t)b * Nc + n) * 64 + j * 2;
    const float2 e0 = *(const float2*)(enc + eb);
    const float2 e1 = *(const float2*)(enc + 4194304 + eb);
    const float s0 = q0 + k0, s1 = q1 + k1;
    const float r0 = s0 * e0.x - s1 * e1.x;
    const float r1 = s1 * e0.y + s0 * e1.y;
    ushort2 o;
    o.x = f2bf((r0 + v0) * (1.f / 3.f));
    o.y = f2bf((r1 + v1) * (1.f / 3.f));
    *(ushort2*)(wi + bn * 256 + h * 64 + j * 2) = o;
}

__global__ __launch_bounds__(256) void zero_kernel(float* __restrict__ p, int n) {
    const int i = blockIdx.x * 256 + threadIdx.x;
    if (i < n) p[i] = 0.f;
}

// norm2[b,c] = sum_n w[b,n,c]^2  (w fp32, lives in d_out)
__global__ __launch_bounds__(256) void colsq_kernel(const float* __restrict__ w,
                                                    float* __restrict__ norm2) {
    const int b = blockIdx.x >> 6;
    const int chunk = blockIdx.x & 63;
    const int c = threadIdx.x;
    const float* base = w + ((size_t)b * Nc + (size_t)chunk * 64) * Cc + c;
    float s = 0.f;
    #pragma unroll 4
    for (int i = 0; i < 64; ++i) { const float v = base[(size_t)i * Cc]; s += v * v; }
    atomicAdd(&norm2[b * Cc + c], s);
}

// per-row: sum_ws -> head softmax -> Pi; accumulate S = sum_n Pi, T = sum_n Pi*raw
__global__ __launch_bounds__(256) void pi_kernel(const float* __restrict__ w,
                                                 const float* __restrict__ norm2,
                                                 const float* __restrict__ temp,
                                                 float* __restrict__ Pi,
                                                 float* __restrict__ S,
                                                 float* __restrict__ T) {
    const int t = threadIdx.x;
    const int i = t & 15;
    const int lr = t >> 4;
    const size_t r = (size_t)blockIdx.x * 16 + lr;
    const int b = (int)(r >> 12);
    const float* wrow = w + r * Cc;
    const float* n2row = norm2 + b * Cc;
    float raw[4], nrm[4];
    #pragma unroll
    for (int h = 0; h < 4; ++h) {
        const float4 wv = *(const float4*)(wrow + h * 64 + i * 4);
        const float4 n2 = *(const float4*)(n2row + h * 64 + i * 4);
        const float s0 = wv.x * wv.x, s1 = wv.y * wv.y, s2 = wv.z * wv.z, s3 = wv.w * wv.w;
        raw[h] = s0 + s1 + s2 + s3;
        nrm[h] = s0 / fmaxf(n2.x, 1e-24f) + s1 / fmaxf(n2.y, 1e-24f)
               + s2 / fmaxf(n2.z, 1e-24f) + s3 / fmaxf(n2.w, 1e-24f);
    }
    #pragma unroll
    for (int off = 1; off < 16; off <<= 1) {
        #pragma unroll
        for (int h = 0; h < 4; ++h) {
            raw[h] += __shfl_xor(raw[h], off, 64);
            nrm[h] += __shfl_xor(nrm[h], off, 64);
        }
    }
    float sw[4], m = -1e30f;
    #pragma unroll
    for (int h = 0; h < 4; ++h) { sw[h] = nrm[h] * temp[h]; m = fmaxf(m, sw[h]); }
    float e[4], Z = 0.f;
    #pragma unroll
    for (int h = 0; h < 4; ++h) { e[h] = expf(sw[h] - m); Z += e[h]; }
    const float invZ = 1.f / Z;
    float pi[4];
    #pragma unroll
    for (int h = 0; h < 4; ++h) pi[h] = e[h] * invZ;
    if (i < 4) Pi[r * 4 + i] = pi[i];

    __shared__ float sS[16][4], sT[16][4];
    if (i == 0) {
        #pragma unroll
        for (int h = 0; h < 4; ++h) { sS[lr][h] = pi[h]; sT[lr][h] = pi[h] * raw[h]; }
    }
    __syncthreads();
    if (t < 4) {
        float as = 0.f, at = 0.f;
        for (int rr = 0; rr < 16; ++rr) { as += sS[rr][t]; at += sT[rr][t]; }
        atomicAdd(&S[b * 4 + t], as);
        atomicAdd(&T[b * 4 + t], at);
    }
}

__global__ void attn_kernel(const float* __restrict__ S, const float* __restrict__ T,
                            float* __restrict__ attn) {
    const int i = threadIdx.x;  // 64
    const float dots = T[i] / (S[i] + 1e-8f);
    attn[i] = 1.f / (1.f + dots);
}

// out = -w * Pi * attn  (w fp32 in, out bf16)
__global__ __launch_bounds__(256) void out_kernel(const float* __restrict__ w,
                                                  const float* __restrict__ Pi,
                                                  const float* __restrict__ attn,
                                                  unsigned short* __restrict__ out) {
    const size_t tid = (size_t)blockIdx.x * 256 + threadIdx.x;
    const size_t r = tid >> 6;
    const int q = (int)(tid & 63);
    const int h = q >> 4;
    const int b = (int)(r >> 12);
    const float p = -Pi[r * 4 + h] * attn[b * 4 + h];
    const float4 wv = *(const float4*)(w + r * Cc + q * 4);
    ushort4 o;
    o.x = f2bf(wv.x * p); o.y = f2bf(wv.y * p);
    o.z = f2bf(wv.z * p); o.w = f2bf(wv.w * p);
    *(ushort4*)(out + r * Cc + q * 4) = o;
}

// LayerNorm(512) + exact gelu, in place on bf16; one wave per row
__global__ __launch_bounds__(256) void ln_gelu_kernel(unsigned short* __restrict__ h1,
                                                      const float* __restrict__ g,
                                                      const float* __restrict__ bb) {
    const int wave = threadIdx.x >> 6, lane = threadIdx.x & 63;
    const size_t row = (size_t)blockIdx.x * 4 + wave;
    unsigned short* p = h1 + row * 512;
    const short8 hv = *(const short8*)(p + lane * 8);
    float va[8];
    float s = 0.f, sq = 0.f;
    #pragma unroll
    for (int k = 0; k < 8; ++k) {
        va[k] = bf2f((unsigned short)hv[k]);
        s += va[k]; sq += va[k] * va[k];
    }
    #pragma unroll
    for (int off = 1; off < 64; off <<= 1) {
        s += __shfl_xor(s, off, 64);
        sq += __shfl_xor(sq, off, 64);
    }
    const float mean = s * (1.f / 512.f);
    const float var = sq * (1.f / 512.f) - mean * mean;
    const float rstd = rsqrtf(var + 1e-5f);
    const float4 g0 = *(const float4*)(g + lane * 8);
    const float4 g1 = *(const float4*)(g + lane * 8 + 4);
    const float4 b0 = *(const float4*)(bb + lane * 8);
    const float4 b1 = *(const float4*)(bb + lane * 8 + 4);
    const float vg[8] = {g0.x, g0.y, g0.z, g0.w, g1.x, g1.y, g1.z, g1.w};
    const float vb[8] = {b0.x, b0.y, b0.z, b0.w, b1.x, b1.y, b1.z, b1.w};
    short8 ov;
    #pragma unroll
    for (int k = 0; k < 8; ++k) {
        const float ln = (va[k] - mean) * rstd * vg[k] + vb[k];
        ov[k] = (short)f2bf(0.5f * ln * (1.f + erff(ln * 0.70710678118654752f)));
    }
    *(short8*)(p + lane * 8) = ov;
}

// ---------------------------------------------------------------------------
extern "C" void kernel_launch(void* const* d_in, const int* in_sizes, int n_in,
                              void* d_out, int out_size, void* d_ws, size_t ws_size,
                              hipStream_t stream) {
    (void)in_sizes; (void)n_in; (void)out_size; (void)ws_size;
    const float* x          = (const float*)d_in[0];
    const float* enc        = (const float*)d_in[1];
    const float* Wqkv_w     = (const float*)d_in[2];
    const float* Wqkv_b     = (const float*)d_in[3];
    const float* tssa_qkv_w = (const float*)d_in[4];
    const float* tssa_qkv_b = (const float*)d_in[5];
    const float* temp       = (const float*)d_in[6];
    const float* tssa_out_w = (const float*)d_in[7];
    const float* tssa_out_b = (const float*)d_in[8];
    const float* out_proj_w = (const float*)d_in[9];
    const float* out_proj_b = (const float*)d_in[10];
    const float* ffn1_w     = (const float*)d_in[11];
    const float* ffn1_b     = (const float*)d_in[12];
    const float* ln_g       = (const float*)d_in[13];
    const float* ln_b       = (const float*)d_in[14];
    const float* ffn2_w     = (const float*)d_in[15];
    const float* ffn2_b     = (const float*)d_in[16];
    float* outp = (float*)d_out;

    const int M = Bc * Nc;  // 65536

    // ---- workspace layout (bytes) ----
    // region A [0, 96MiB): qkv_bf (M x 768 bf16); later message_bf (A+0, 32MiB)
    //                      and h1_bf (A+32MiB, 64MiB)
    // region B [96MiB, 128MiB): wi_bf (M x 256 bf16); later out_bf
    // stats    [128MiB, ~129.3MiB): fp32 Pi / norm2 / S / T / attn / Wf / bfb
    char* ws = (char*)d_ws;
    unsigned short* qkv_bf     = (unsigned short*)(ws);
    unsigned short* message_bf = (unsigned short*)(ws);
    unsigned short* h1_bf      = (unsigned short*)(ws + 33554432);
    unsigned short* wi_bf      = (unsigned short*)(ws + 100663296);
    unsigned short* out_bf     = wi_bf;
    float* stats = (float*)(ws + 134217728);
    float* Pi    = stats;           // 262144
    float* norm2 = Pi + 262144;     // 4096
    float* Sb    = norm2 + 4096;    // 64
    float* Tb    = Sb + 64;         // 64
    float* attnb = Tb + 64;         // 64
    float* Wf    = attnb + 64;      // 65536
    float* bfb   = Wf + 65536;      // 256
    float* wbuf  = (float*)d_out;   // w fp32 (M x 256), dead before final GEMM

    // fused out-projection weight/bias
    wf_kernel<<<256, 256, 0, stream>>>(out_proj_w, tssa_out_w, Wf);
    bf_kernel<<<1, 256, 0, stream>>>(out_proj_w, tssa_out_b, out_proj_b, bfb);

    // qkv = x @ Wqkv_w^T + b  -> bf16
    gemm_t<float, float, unsigned short><<<dim3(M / BM, 768 / BN), 256, 0, stream>>>(
        x, 256, x, 256, 256, Wqkv_w, Wqkv_b, nullptr, qkv_bf, M, 768, 256);

    // w_input = (rope(q)+rope(k)+v)/3 -> bf16
    rope_kernel<<<32768, 256, 0, stream>>>(qkv_bf, enc, wi_bf);

    // w = w_input @ tssa_qkv_w^T + b -> fp32 (in d_out)
    gemm_t<unsigned short, unsigned short, float><<<dim3(M / BM, 256 / BN), 256, 0, stream>>>(
        wi_bf, 256, wi_bf, 256, 256, tssa_qkv_w, tssa_qkv_b, nullptr, wbuf, M, 256, 256);

    // stats
    zero_kernel<<<17, 256, 0, stream>>>(norm2, 4096 + 64 + 64);
    colsq_kernel<<<1024, 256, 0, stream>>>(wbuf, norm2);
    pi_kernel<<<4096, 256, 0, stream>>>(wbuf, norm2, temp, Pi, Sb, Tb);
    attn_kernel<<<1, 64, 0, stream>>>(Sb, Tb, attnb);

    // out = -w * Pi * attn -> bf16 (region B)
    out_kernel<<<16384, 256, 0, stream>>>(wbuf, Pi, attnb, out_bf);

    // message = out @ Wf^T + bf -> bf16 (region A head)
    gemm_t<unsigned short, unsigned short, unsigned short><<<dim3(M / BM, 256 / BN), 256, 0, stream>>>(
        out_bf, 256, out_bf, 256, 256, Wf, bfb, nullptr, message_bf, M, 256, 256);

    // h1 = [x, message] @ ffn1_w^T + b -> bf16 (region A tail)
    gemm_t<float, unsigned short, unsigned short><<<dim3(M / BM, 512 / BN), 256, 0, stream>>>(
        x, 256, message_bf, 256, 256, ffn1_w, ffn1_b, nullptr, h1_bf, M, 512, 512);

    // LN + gelu in place
    ln_gelu_kernel<<<16384, 256, 0, stream>>>(h1_bf, ln_g, ln_b);

    // out = x + g @ ffn2_w^T + b -> fp32 (d_out; h1/w both dead)
    gemm_t<unsigned short, unsigned short, float><<<dim3(M / BM, 256 / BN), 256, 0, stream>>>(
        h1_bf, 512, h1_bf, 512, 512, ffn2_w, ffn2_b, x, outp, M, 256, 512);
}

// Round 3
// 565.580 us; speedup vs baseline: 1.2446x; 1.2446x over previous
//
#include <hip/hip_runtime.h>
#include <math.h>

#define Bc 16
#define Nc 4096
#define Cc 256

typedef __attribute__((ext_vector_type(8))) short short8;
typedef __attribute__((ext_vector_type(4))) float floatx4;

__device__ __forceinline__ unsigned short f2bf(float f) {
    union { float f; unsigned int u; } v; v.f = f;
    unsigned int u = v.u;
    return (unsigned short)((u + 0x7fffu + ((u >> 16) & 1u)) >> 16);
}
__device__ __forceinline__ float bf2f(unsigned short u) {
    union { unsigned int u; float f; } v; v.u = ((unsigned int)u) << 16;
    return v.f;
}
__device__ __forceinline__ void storeC(float* C, size_t idx, float v) { C[idx] = v; }
__device__ __forceinline__ void storeC(unsigned short* C, size_t idx, float v) { C[idx] = f2bf(v); }

// async global->LDS, 16 bytes per lane; LDS dest must be wave-uniform base + lane*16
__device__ __forceinline__ void gll16(const unsigned short* g, unsigned short* l) {
    __builtin_amdgcn_global_load_lds(
        (const __attribute__((address_space(1))) void*)g,
        (__attribute__((address_space(3))) void*)l,
        16, 0, 0);
}

// ---------------------------------------------------------------------------
// Generic bf16 GEMM: C[M,N] = concat_K(A0,A1)[M,K] @ W[N,K]^T + bias (+res)
// EPI 0: plain (+optional fp32 residual)
// EPI 1: store bf16 w + fused column sum-of-squares (norm2, fp32 acc)
// EPI 2: A staged with per-(row,head-of-k) scale -Pi*attn (VGPR staging path)
// 128x128 tile, BK=32, 4 waves 2x2, each wave 64x64 (4x4 mfma 16x16x32 bf16)
// grid: (N/128, M/128)  -> blockIdx.x = bn (fast) for A-tile L2 reuse
// ---------------------------------------------------------------------------
template <int EPI, typename TOUT>
__global__ __launch_bounds__(256) void gemm_bf(
    const unsigned short* __restrict__ A0, int lda0,
    const unsigned short* __restrict__ A1, int lda1, int K0,
    const unsigned short* __restrict__ W,   // N x K bf16
    const float* __restrict__ bias,         // N
    const float* __restrict__ residual,     // M x N fp32 or null (EPI 0)
    const float* __restrict__ Pi,           // EPI 2: M x 4
    const float* __restrict__ attnb,        // EPI 2: 64
    float* __restrict__ norm2,              // EPI 1: B x 256
    TOUT* __restrict__ C,
    int N, int K)
{
    __shared__ alignas(16) unsigned short As[128 * 32];
    __shared__ alignas(16) unsigned short Ws[128 * 32];

    const int t = threadIdx.x;
    const int bn = blockIdx.x, bm = blockIdx.y;
    const int lane = t & 63, wave = t >> 6;
    const int wm = wave >> 1, wn = wave & 1;
    const int quad = lane >> 4, l16 = lane & 15;
    const int rA = t >> 2, cA = (t & 3) * 8;

    floatx4 acc[4][4];
    #pragma unroll
    for (int i = 0; i < 4; ++i)
        #pragma unroll
        for (int j = 0; j < 4; ++j)
            acc[i][j] = (floatx4){0.f, 0.f, 0.f, 0.f};

    for (int k0 = 0; k0 < K; k0 += 32) {
        #pragma unroll
        for (int hh = 0; hh < 2; ++hh) {
            const size_t grow = (size_t)bm * 128 + rA + hh * 64;
            const int col = k0 + cA;
            if constexpr (EPI == 2) {
                const int b = (int)(grow >> 12);
                const int hd = col >> 6;
                const float sc = -Pi[grow * 4 + hd] * attnb[b * 4 + hd];
                const short8 a = *(const short8*)(A0 + grow * (size_t)lda0 + col);
                short8 o;
                #pragma unroll
                for (int j = 0; j < 8; ++j) o[j] = (short)f2bf(bf2f((unsigned short)a[j]) * sc);
                *(short8*)(&As[t * 8 + hh * 2048]) = o;
            } else {
                const unsigned short* src = (col < K0)
                    ? (A0 + grow * (size_t)lda0 + col)
                    : (A1 + grow * (size_t)lda1 + (col - K0));
                gll16(src, &As[t * 8 + hh * 2048]);
            }
            const size_t wrow = (size_t)bn * 128 + rA + hh * 64;
            gll16(W + wrow * (size_t)K + k0 + cA, &Ws[t * 8 + hh * 2048]);
        }
        __syncthreads();

        short8 af[4], wf[4];
        #pragma unroll
        for (int i = 0; i < 4; ++i)
            af[i] = *(const short8*)(&As[(wm * 64 + i * 16 + l16) * 32 + quad * 8]);
        #pragma unroll
        for (int i = 0; i < 4; ++i)
            wf[i] = *(const short8*)(&Ws[(wn * 64 + i * 16 + l16) * 32 + quad * 8]);
        #pragma unroll
        for (int mi = 0; mi < 4; ++mi)
            #pragma unroll
            for (int ni = 0; ni < 4; ++ni)
                acc[mi][ni] = __builtin_amdgcn_mfma_f32_16x16x32_bf16(
                    af[mi], wf[ni], acc[mi][ni], 0, 0, 0);
        __syncthreads();
    }

    // epilogue: C/D layout col = lane&15 (W side), row = quad*4 + reg (A side)
    #pragma unroll
    for (int ni = 0; ni < 4; ++ni) {
        const int cg = bn * 128 + wn * 64 + ni * 16 + l16;
        const float bv = bias[cg];
        float ss = 0.f;
        #pragma unroll
        for (int mi = 0; mi < 4; ++mi) {
            const int rowb = bm * 128 + wm * 64 + mi * 16 + quad * 4;
            #pragma unroll
            for (int rg = 0; rg < 4; ++rg) {
                const size_t row = (size_t)rowb + rg;
                float v = acc[mi][ni][rg] + bv;
                if constexpr (EPI == 0) {
                    if (residual) v += residual[row * (size_t)N + cg];
                }
                if constexpr (EPI == 1) ss += v * v;
                storeC(C, row * (size_t)N + cg, v);
            }
        }
        if constexpr (EPI == 1) {
            ss += __shfl_xor(ss, 16, 64);
            ss += __shfl_xor(ss, 32, 64);
            if (quad == 0) atomicAdd(&norm2[(bm >> 5) * 256 + cg], ss);
        }
    }
}

// ---------------------------------------------------------------------------
// GEMM1: [s|v] = x_bf @ [Wqk;Wv]^T + b, rope fused in epilogue -> wi bf16
// Each block: 128 rows x 128 wi-cols, dual accumulators (s and v).
// ---------------------------------------------------------------------------
__global__ __launch_bounds__(256) void gemm_rope(
    const unsigned short* __restrict__ A,    // x_bf, lda 256
    const unsigned short* __restrict__ Wsv,  // 512 x 256 bf16 (s: rows 0-255, v: 256-511)
    const float* __restrict__ bsv,           // 512
    const float* __restrict__ enc,           // fp32 (2,B,1,N,64)
    unsigned short* __restrict__ wi)         // M x 256
{
    __shared__ alignas(16) unsigned short As[128 * 32];
    __shared__ alignas(16) unsigned short Ss[128 * 32];
    __shared__ alignas(16) unsigned short Vs[128 * 32];

    const int t = threadIdx.x;
    const int bn = blockIdx.x;  // 0..1
    const int bm = blockIdx.y;  // 0..511
    const int lane = t & 63, wave = t >> 6;
    const int wm = wave >> 1, wn = wave & 1;
    const int quad = lane >> 4, l16 = lane & 15;
    const int rA = t >> 2, cA = (t & 3) * 8;

    floatx4 accs[4][4], accv[4][4];
    #pragma unroll
    for (int i = 0; i < 4; ++i)
        #pragma unroll
        for (int j = 0; j < 4; ++j) {
            accs[i][j] = (floatx4){0.f, 0.f, 0.f, 0.f};
            accv[i][j] = (floatx4){0.f, 0.f, 0.f, 0.f};
        }

    for (int k0 = 0; k0 < 256; k0 += 32) {
        #pragma unroll
        for (int hh = 0; hh < 2; ++hh) {
            const int r = rA + hh * 64;
            gll16(A + ((size_t)bm * 128 + r) * 256 + k0 + cA, &As[t * 8 + hh * 2048]);
            gll16(Wsv + (size_t)(bn * 128 + r) * 256 + k0 + cA, &Ss[t * 8 + hh * 2048]);
            gll16(Wsv + (size_t)(256 + bn * 128 + r) * 256 + k0 + cA, &Vs[t * 8 + hh * 2048]);
        }
        __syncthreads();

        short8 af[4], sf[4], vf[4];
        #pragma unroll
        for (int i = 0; i < 4; ++i) {
            af[i] = *(const short8*)(&As[(wm * 64 + i * 16 + l16) * 32 + quad * 8]);
            sf[i] = *(const short8*)(&Ss[(wn * 64 + i * 16 + l16) * 32 + quad * 8]);
            vf[i] = *(const short8*)(&Vs[(wn * 64 + i * 16 + l16) * 32 + quad * 8]);
        }
        #pragma unroll
        for (int mi = 0; mi < 4; ++mi)
            #pragma unroll
            for (int ni = 0; ni < 4; ++ni) {
                accs[mi][ni] = __builtin_amdgcn_mfma_f32_16x16x32_bf16(af[mi], sf[ni], accs[mi][ni], 0, 0, 0);
                accv[mi][ni] = __builtin_amdgcn_mfma_f32_16x16x32_bf16(af[mi], vf[ni], accv[mi][ni], 0, 0, 0);
            }
        __syncthreads();
    }

    // epilogue: rope-combine.  cg in [0,256): head h=cg>>6, d=cg&63.
    #pragma unroll
    for (int ni = 0; ni < 4; ++ni) {
        const int cg = bn * 128 + wn * 64 + ni * 16 + l16;
        const int d = cg & 63;
        const float sign = (d & 1) ? 1.f : -1.f;
        const float bs = bsv[cg], bv = bsv[256 + cg];
        #pragma unroll
        for (int mi = 0; mi < 4; ++mi) {
            const int rowb = bm * 128 + wm * 64 + mi * 16 + quad * 4;
            #pragma unroll
            for (int rg = 0; rg < 4; ++rg) {
                const size_t row = (size_t)rowb + rg;
                const float sv = accs[mi][ni][rg] + bs;
                const float vv = accv[mi][ni][rg] + bv;
                const float partner = __shfl_xor(sv, 1, 64);  // col cg^1, same row
                const size_t eo = row * 64 + d;               // (b*4096+n)*64+d
                const float e0 = enc[eo];
                const float e1 = enc[4194304 + eo];
                const float r = sv * e0 + sign * partner * e1;
                wi[row * 256 + cg] = f2bf((r + vv) * (1.f / 3.f));
            }
        }
    }
}

// ---------------------------------------------------------------------------
// prep kernels
// ---------------------------------------------------------------------------
__global__ __launch_bounds__(256) void conv_bf(const float* __restrict__ src,
                                               unsigned short* __restrict__ dst, int n8) {
    const int i = blockIdx.x * 256 + threadIdx.x;
    if (i >= n8) return;
    const float4 f0 = *(const float4*)(src + (size_t)i * 8);
    const float4 f1 = *(const float4*)(src + (size_t)i * 8 + 4);
    short8 sv;
    sv[0] = (short)f2bf(f0.x); sv[1] = (short)f2bf(f0.y);
    sv[2] = (short)f2bf(f0.z); sv[3] = (short)f2bf(f0.w);
    sv[4] = (short)f2bf(f1.x); sv[5] = (short)f2bf(f1.y);
    sv[6] = (short)f2bf(f1.z); sv[7] = (short)f2bf(f1.w);
    *(short8*)(dst + (size_t)i * 8) = sv;
}

// Wsv rows 0-255: Wq+Wk (head-major), rows 256-511: Wv; bsv likewise
__global__ __launch_bounds__(256) void prep_wsv(const float* __restrict__ Wqkv,
                                                const float* __restrict__ bqkv,
                                                unsigned short* __restrict__ Wsv,
                                                float* __restrict__ bsv) {
    const int r = blockIdx.x;   // 0..511
    const int c = threadIdx.x;  // 0..255
    const int cd = r & 255;
    const int h = cd >> 6, dd = cd & 63;
    const int base = h * 192 + dd * 3;
    if (r < 256) {
        Wsv[r * 256 + c] = f2bf(Wqkv[(base + 0) * 256 + c] + Wqkv[(base + 1) * 256 + c]);
        if (c == 0) bsv[r] = bqkv[base] + bqkv[base + 1];
    } else {
        Wsv[r * 256 + c] = f2bf(Wqkv[(base + 2) * 256 + c]);
        if (c == 0) bsv[r] = bqkv[base + 2];
    }
}

// Wf = out_proj_w @ tssa_out_w -> bf16; bfb = out_proj_w @ tssa_out_b + out_proj_b
__global__ __launch_bounds__(256) void wf_kernel(const float* __restrict__ op,
                                                 const float* __restrict__ to,
                                                 unsigned short* __restrict__ Wf) {
    const int i = blockIdx.x, j = threadIdx.x;
    float s = 0.f;
    for (int k = 0; k < 256; ++k) s += op[i * 256 + k] * to[k * 256 + j];
    Wf[i * 256 + j] = f2bf(s);
}
__global__ void bf_kernel(const float* __restrict__ op,
                          const float* __restrict__ tob,
                          const float* __restrict__ opb,
                          float* __restrict__ bf) {
    const int i = threadIdx.x;  // 256
    float s = opb[i];
    for (int k = 0; k < 256; ++k) s += op[i * 256 + k] * tob[k];
    bf[i] = s;
}

__global__ __launch_bounds__(256) void zero_kernel(float* __restrict__ p, int n) {
    const int i = blockIdx.x * 256 + threadIdx.x;
    if (i < n) p[i] = 0.f;
}

// per-row softmax over heads + S/T accumulation (w is bf16 now)
__global__ __launch_bounds__(256) void pi_kernel(const unsigned short* __restrict__ w,
                                                 const float* __restrict__ norm2,
                                                 const float* __restrict__ temp,
                                                 float* __restrict__ Pi,
                                                 float* __restrict__ S,
                                                 float* __restrict__ T) {
    const int t = threadIdx.x;
    const int i = t & 15;
    const int lr = t >> 4;
    const size_t r = (size_t)blockIdx.x * 16 + lr;
    const int b = (int)(r >> 12);
    const unsigned short* wrow = w + r * Cc;
    const float* n2row = norm2 + b * Cc;
    float raw[4], nrm[4];
    #pragma unroll
    for (int h = 0; h < 4; ++h) {
        const ushort4 wv = *(const ushort4*)(wrow + h * 64 + i * 4);
        const float w0 = bf2f(wv.x), w1 = bf2f(wv.y), w2 = bf2f(wv.z), w3 = bf2f(wv.w);
        const float4 n2 = *(const float4*)(n2row + h * 64 + i * 4);
        const float s0 = w0 * w0, s1 = w1 * w1, s2 = w2 * w2, s3 = w3 * w3;
        raw[h] = s0 + s1 + s2 + s3;
        nrm[h] = s0 / fmaxf(n2.x, 1e-24f) + s1 / fmaxf(n2.y, 1e-24f)
               + s2 / fmaxf(n2.z, 1e-24f) + s3 / fmaxf(n2.w, 1e-24f);
    }
    #pragma unroll
    for (int off = 1; off < 16; off <<= 1) {
        #pragma unroll
        for (int h = 0; h < 4; ++h) {
            raw[h] += __shfl_xor(raw[h], off, 64);
            nrm[h] += __shfl_xor(nrm[h], off, 64);
        }
    }
    float sw[4], m = -1e30f;
    #pragma unroll
    for (int h = 0; h < 4; ++h) { sw[h] = nrm[h] * temp[h]; m = fmaxf(m, sw[h]); }
    float e[4], Z = 0.f;
    #pragma unroll
    for (int h = 0; h < 4; ++h) { e[h] = expf(sw[h] - m); Z += e[h]; }
    const float invZ = 1.f / Z;
    float pi[4];
    #pragma unroll
    for (int h = 0; h < 4; ++h) pi[h] = e[h] * invZ;
    if (i < 4) Pi[r * 4 + i] = pi[i];

    __shared__ float sS[16][4], sT[16][4];
    if (i == 0) {
        #pragma unroll
        for (int h = 0; h < 4; ++h) { sS[lr][h] = pi[h]; sT[lr][h] = pi[h] * raw[h]; }
    }
    __syncthreads();
    if (t < 4) {
        float as = 0.f, at = 0.f;
        for (int rr = 0; rr < 16; ++rr) { as += sS[rr][t]; at += sT[rr][t]; }
        atomicAdd(&S[b * 4 + t], as);
        atomicAdd(&T[b * 4 + t], at);
    }
}

__global__ void attn_kernel(const float* __restrict__ S, const float* __restrict__ T,
                            float* __restrict__ attn) {
    const int i = threadIdx.x;  // 64
    const float dots = T[i] / (S[i] + 1e-8f);
    attn[i] = 1.f / (1.f + dots);
}

// LayerNorm(512) + exact gelu, in place on bf16; one wave per row
__global__ __launch_bounds__(256) void ln_gelu_kernel(unsigned short* __restrict__ h1,
                                                      const float* __restrict__ g,
                                                      const float* __restrict__ bb) {
    const int wave = threadIdx.x >> 6, lane = threadIdx.x & 63;
    const size_t row = (size_t)blockIdx.x * 4 + wave;
    unsigned short* p = h1 + row * 512;
    const short8 hv = *(const short8*)(p + lane * 8);
    float va[8];
    float s = 0.f, sq = 0.f;
    #pragma unroll
    for (int k = 0; k < 8; ++k) {
        va[k] = bf2f((unsigned short)hv[k]);
        s += va[k]; sq += va[k] * va[k];
    }
    #pragma unroll
    for (int off = 1; off < 64; off <<= 1) {
        s += __shfl_xor(s, off, 64);
        sq += __shfl_xor(sq, off, 64);
    }
    const float mean = s * (1.f / 512.f);
    const float var = sq * (1.f / 512.f) - mean * mean;
    const float rstd = rsqrtf(var + 1e-5f);
    const float4 g0 = *(const float4*)(g + lane * 8);
    const float4 g1 = *(const float4*)(g + lane * 8 + 4);
    const float4 b0 = *(const float4*)(bb + lane * 8);
    const float4 b1 = *(const float4*)(bb + lane * 8 + 4);
    const float vg[8] = {g0.x, g0.y, g0.z, g0.w, g1.x, g1.y, g1.z, g1.w};
    const float vb[8] = {b0.x, b0.y, b0.z, b0.w, b1.x, b1.y, b1.z, b1.w};
    short8 ov;
    #pragma unroll
    for (int k = 0; k < 8; ++k) {
        const float ln = (va[k] - mean) * rstd * vg[k] + vb[k];
        ov[k] = (short)f2bf(0.5f * ln * (1.f + erff(ln * 0.70710678118654752f)));
    }
    *(short8*)(p + lane * 8) = ov;
}

// ---------------------------------------------------------------------------
extern "C" void kernel_launch(void* const* d_in, const int* in_sizes, int n_in,
                              void* d_out, int out_size, void* d_ws, size_t ws_size,
                              hipStream_t stream) {
    (void)in_sizes; (void)n_in; (void)out_size; (void)ws_size;
    const float* x          = (const float*)d_in[0];
    const float* enc        = (const float*)d_in[1];
    const float* Wqkv_w     = (const float*)d_in[2];
    const float* Wqkv_b     = (const float*)d_in[3];
    const float* tssa_qkv_w = (const float*)d_in[4];
    const float* tssa_qkv_b = (const float*)d_in[5];
    const float* temp       = (const float*)d_in[6];
    const float* tssa_out_w = (const float*)d_in[7];
    const float* tssa_out_b = (const float*)d_in[8];
    const float* out_proj_w = (const float*)d_in[9];
    const float* out_proj_b = (const float*)d_in[10];
    const float* ffn1_w     = (const float*)d_in[11];
    const float* ffn1_b     = (const float*)d_in[12];
    const float* ln_g       = (const float*)d_in[13];
    const float* ln_b       = (const float*)d_in[14];
    const float* ffn2_w     = (const float*)d_in[15];
    const float* ffn2_b     = (const float*)d_in[16];
    float* outp = (float*)d_out;

    const int M = Bc * Nc;  // 65536

    // ---- workspace layout (MiB offsets) ----
    // [0,32)   x_bf          [32,64)  wi_bf      [64,96)  w_bf
    // [96,128) message_bf    [32,96)  h1_bf (aliases wi+w, both dead by then)
    // [128,..) stats + bf16 weights (~2.4 MB)
    char* ws = (char*)d_ws;
    unsigned short* x_bf   = (unsigned short*)(ws);
    unsigned short* wi_bf  = (unsigned short*)(ws + (size_t)(32 << 20));
    unsigned short* w_bf   = (unsigned short*)(ws + (size_t)(64 << 20));
    unsigned short* h1_bf  = (unsigned short*)(ws + (size_t)(32 << 20));
    unsigned short* msg_bf = (unsigned short*)(ws + (size_t)(96 << 20));
    float* sb   = (float*)(ws + (size_t)(128 << 20));
    float* Pi    = sb;               // 262144
    float* norm2 = Pi + 262144;      // 4096
    float* Sb    = norm2 + 4096;     // 64
    float* Tb    = Sb + 64;          // 64
    float* attnb = Tb + 64;          // 64
    float* bsv   = attnb + 64;       // 512
    float* bfb   = bsv + 512;        // 256
    unsigned short* Wsv_bf  = (unsigned short*)(bfb + 256);   // 512x256
    unsigned short* tssa_bf = Wsv_bf + 131072;                // 256x256
    unsigned short* Wf_bf   = tssa_bf + 65536;                // 256x256
    unsigned short* ffn1_bf = Wf_bf + 65536;                  // 512x512
    unsigned short* ffn2_bf = ffn1_bf + 262144;               // 256x512

    // ---- prep: bf16 conversions + fused weights ----
    conv_bf<<<8192, 256, 0, stream>>>(x, x_bf, M * 256 / 8);
    prep_wsv<<<512, 256, 0, stream>>>(Wqkv_w, Wqkv_b, Wsv_bf, bsv);
    wf_kernel<<<256, 256, 0, stream>>>(out_proj_w, tssa_out_w, Wf_bf);
    bf_kernel<<<1, 256, 0, stream>>>(out_proj_w, tssa_out_b, out_proj_b, bfb);
    conv_bf<<<32, 256, 0, stream>>>(tssa_qkv_w, tssa_bf, 65536 / 8);
    conv_bf<<<128, 256, 0, stream>>>(ffn1_w, ffn1_bf, 262144 / 8);
    conv_bf<<<64, 256, 0, stream>>>(ffn2_w, ffn2_bf, 131072 / 8);
    zero_kernel<<<17, 256, 0, stream>>>(norm2, 4096 + 128);

    // G1: wi = rope-combine(x_bf @ [Wqk;Wv]^T + b)
    gemm_rope<<<dim3(2, M / 128), 256, 0, stream>>>(x_bf, Wsv_bf, bsv, enc, wi_bf);

    // G2: w = wi @ tssa^T + b  -> bf16, fused colsq into norm2
    gemm_bf<1, unsigned short><<<dim3(2, M / 128), 256, 0, stream>>>(
        wi_bf, 256, wi_bf, 256, 256, tssa_bf, tssa_qkv_b, nullptr,
        nullptr, nullptr, norm2, w_bf, 256, 256);

    // stats
    pi_kernel<<<4096, 256, 0, stream>>>(w_bf, norm2, temp, Pi, Sb, Tb);
    attn_kernel<<<1, 64, 0, stream>>>(Sb, Tb, attnb);

    // G3: message = (-w*Pi*attn) @ Wf^T + bfb  (scale fused in A-staging)
    gemm_bf<2, unsigned short><<<dim3(2, M / 128), 256, 0, stream>>>(
        w_bf, 256, w_bf, 256, 256, Wf_bf, bfb, nullptr,
        Pi, attnb, nullptr, msg_bf, 256, 256);

    // G4: h1 = [x_bf, message] @ ffn1^T + b
    gemm_bf<0, unsigned short><<<dim3(4, M / 128), 256, 0, stream>>>(
        x_bf, 256, msg_bf, 256, 256, ffn1_bf, ffn1_b, nullptr,
        nullptr, nullptr, nullptr, h1_bf, 512, 512);

    // LN + gelu in place
    ln_gelu_kernel<<<16384, 256, 0, stream>>>(h1_bf, ln_g, ln_b);

    // G5: out = x + g @ ffn2^T + b  (fp32 out)
    gemm_bf<0, float><<<dim3(2, M / 128), 256, 0, stream>>>(
        h1_bf, 512, h1_bf, 512, 512, ffn2_bf, ffn2_b, x,
        nullptr, nullptr, nullptr, outp, 256, 512);
}

// Round 4
// 511.961 us; speedup vs baseline: 1.3750x; 1.1047x over previous
//
#include <hip/hip_runtime.h>
#include <math.h>

#define Bc 16
#define Nc 4096

typedef __attribute__((ext_vector_type(8))) short short8;
typedef __attribute__((ext_vector_type(4))) float floatx4;

__device__ __forceinline__ unsigned short f2bf(float f) {
    union { float f; unsigned int u; } v; v.f = f;
    unsigned int u = v.u;
    return (unsigned short)((u + 0x7fffu + ((u >> 16) & 1u)) >> 16);
}
__device__ __forceinline__ float bf2f(unsigned short u) {
    union { unsigned int u; float f; } v; v.u = ((unsigned int)u) << 16;
    return v.f;
}

// async global->LDS 16B per lane; LDS dest must be wave-uniform base + lane*16
__device__ __forceinline__ void gll16(const unsigned short* g, unsigned short* l) {
    __builtin_amdgcn_global_load_lds(
        (const __attribute__((address_space(1))) void*)g,
        (__attribute__((address_space(3))) void*)l,
        16, 0, 0);
}

// ---------------------------------------------------------------------------
// Swapped-operand bf16 GEMM: C[M,N] = concat(A0,A1)[M,K] @ W[N,K]^T + bias
// mfma(wf, af, acc): D col = quad*4+rg (4 consecutive -> ushort4/float4 store),
// D row = l16. BK=64 with kseg^=(row&7) granule swizzle (gll16-compatible,
// conflict-free b128 fragment reads).
// EPI 1: + fused column sum-of-squares -> norm2 (fp32)
// EPI 2: A staged with scale -Pi*attn (VALU path)
// EPI 3: A staged with LN+gelu from rowstats (VALU path); bf16 residual; fp32 out
// EPI 4: + fused per-row sum/sumsq -> rowstats (atomics)
// grid: (N/128, M/128), bn fastest for A-tile L2 reuse.
// ---------------------------------------------------------------------------
template <int EPI, typename TOUT>
__global__ __launch_bounds__(256) void gemm_bf(
    const unsigned short* __restrict__ A0, int lda0,
    const unsigned short* __restrict__ A1, int lda1, int K0,
    const unsigned short* __restrict__ W,
    const float* __restrict__ bias,
    const unsigned short* __restrict__ resid_bf,   // EPI3
    const float* __restrict__ Pi,                  // EPI2
    const float* __restrict__ attnb,               // EPI2
    const float* __restrict__ lnstats,             // EPI3: float2 per row
    const float* __restrict__ ln_g,                // EPI3
    const float* __restrict__ ln_b,                // EPI3
    float* __restrict__ norm2,                     // EPI1
    float* __restrict__ rowstats,                  // EPI4: float2 per row
    TOUT* __restrict__ C, int N, int K)
{
    __shared__ alignas(16) unsigned short As[128 * 64];
    __shared__ alignas(16) unsigned short Bs[128 * 64];

    const int t = threadIdx.x;
    const int bn = blockIdx.x, bm = blockIdx.y;
    const int lane = t & 63, wave = t >> 6;
    const int wm = wave >> 1, wn = wave & 1;
    const int quad = lane >> 4, l16 = lane & 15;
    const int rt = t >> 3, st = t & 7;

    floatx4 acc[4][4];
    #pragma unroll
    for (int i = 0; i < 4; ++i)
        #pragma unroll
        for (int j = 0; j < 4; ++j)
            acc[i][j] = (floatx4){0.f, 0.f, 0.f, 0.f};

    for (int k0 = 0; k0 < K; k0 += 64) {
        #pragma unroll
        for (int hh = 0; hh < 4; ++hh) {
            const int row = hh * 32 + rt;
            const int kseg = st ^ (row & 7);
            const int col = k0 + kseg * 8;
            unsigned short* ldsa = As + row * 64 + st * 8;
            const size_t grow = (size_t)bm * 128 + row;
            if constexpr (EPI == 2) {
                const int b = (int)(grow >> 12);
                const int hd = col >> 6;
                const float sc = -Pi[grow * 4 + hd] * attnb[b * 4 + hd];
                const short8 a = *(const short8*)(A0 + grow * (size_t)lda0 + col);
                short8 o;
                #pragma unroll
                for (int j = 0; j < 8; ++j) o[j] = (short)f2bf(bf2f((unsigned short)a[j]) * sc);
                *(short8*)ldsa = o;
            } else if constexpr (EPI == 3) {
                const float2 stv = *(const float2*)(lnstats + grow * 2);
                const float mean = stv.x * (1.f / 512.f);
                const float var = stv.y * (1.f / 512.f) - mean * mean;
                const float rstd = rsqrtf(var + 1e-5f);
                const short8 a = *(const short8*)(A0 + grow * (size_t)lda0 + col);
                const float4 g0 = *(const float4*)(ln_g + col);
                const float4 g1 = *(const float4*)(ln_g + col + 4);
                const float4 b0 = *(const float4*)(ln_b + col);
                const float4 b1 = *(const float4*)(ln_b + col + 4);
                const float vg[8] = {g0.x, g0.y, g0.z, g0.w, g1.x, g1.y, g1.z, g1.w};
                const float vb[8] = {b0.x, b0.y, b0.z, b0.w, b1.x, b1.y, b1.z, b1.w};
                short8 o;
                #pragma unroll
                for (int j = 0; j < 8; ++j) {
                    const float ln = (bf2f((unsigned short)a[j]) - mean) * rstd * vg[j] + vb[j];
                    o[j] = (short)f2bf(0.5f * ln * (1.f + erff(ln * 0.70710678118654752f)));
                }
                *(short8*)ldsa = o;
            } else {
                const unsigned short* src = (col < K0)
                    ? (A0 + grow * (size_t)lda0 + col)
                    : (A1 + grow * (size_t)lda1 + (col - K0));
                gll16(src, ldsa);
            }
            gll16(W + ((size_t)bn * 128 + row) * (size_t)K + col, Bs + row * 64 + st * 8);
        }
        __syncthreads();
        #pragma unroll
        for (int kk = 0; kk < 2; ++kk) {
            short8 af[4], wf[4];
            #pragma unroll
            for (int i = 0; i < 4; ++i) {
                const int ra = wm * 64 + i * 16 + l16;
                af[i] = *(const short8*)(As + ra * 64 + ((quad + kk * 4) ^ (ra & 7)) * 8);
                const int rw = wn * 64 + i * 16 + l16;
                wf[i] = *(const short8*)(Bs + rw * 64 + ((quad + kk * 4) ^ (rw & 7)) * 8);
            }
            #pragma unroll
            for (int mi = 0; mi < 4; ++mi)
                #pragma unroll
                for (int ni = 0; ni < 4; ++ni)
                    acc[mi][ni] = __builtin_amdgcn_mfma_f32_16x16x32_bf16(
                        wf[ni], af[mi], acc[mi][ni], 0, 0, 0);
        }
        __syncthreads();
    }

    // ---- epilogue: row = bm*128+wm*64+mi*16+l16; col = bn*128+wn*64+ni*16+quad*4+rg
    float cs[4][4];   // EPI1 col sums
    float rs[4], rq[4];  // EPI4 row sums
    if constexpr (EPI == 1) {
        #pragma unroll
        for (int n = 0; n < 4; ++n)
            #pragma unroll
            for (int r = 0; r < 4; ++r) cs[n][r] = 0.f;
    }
    if constexpr (EPI == 4) {
        #pragma unroll
        for (int m = 0; m < 4; ++m) { rs[m] = 0.f; rq[m] = 0.f; }
    }

    #pragma unroll
    for (int mi = 0; mi < 4; ++mi) {
        const size_t row = (size_t)bm * 128 + wm * 64 + mi * 16 + l16;
        #pragma unroll
        for (int ni = 0; ni < 4; ++ni) {
            const int cb = bn * 128 + wn * 64 + ni * 16 + quad * 4;
            const float4 b4 = *(const float4*)(bias + cb);
            float v[4] = {acc[mi][ni][0] + b4.x, acc[mi][ni][1] + b4.y,
                          acc[mi][ni][2] + b4.z, acc[mi][ni][3] + b4.w};
            if constexpr (EPI == 3) {
                const ushort4 xr = *(const ushort4*)(resid_bf + row * (size_t)N + cb);
                v[0] += bf2f(xr.x); v[1] += bf2f(xr.y);
                v[2] += bf2f(xr.z); v[3] += bf2f(xr.w);
            }
            if constexpr (EPI == 1) {
                #pragma unroll
                for (int rg = 0; rg < 4; ++rg) cs[ni][rg] += v[rg] * v[rg];
            }
            if constexpr (EPI == 4) {
                #pragma unroll
                for (int rg = 0; rg < 4; ++rg) { rs[mi] += v[rg]; rq[mi] += v[rg] * v[rg]; }
            }
            if constexpr (__is_same(TOUT, float)) {
                float4 o; o.x = v[0]; o.y = v[1]; o.z = v[2]; o.w = v[3];
                *(float4*)(C + row * (size_t)N + cb) = o;
            } else {
                ushort4 o;
                o.x = f2bf(v[0]); o.y = f2bf(v[1]); o.z = f2bf(v[2]); o.w = f2bf(v[3]);
                *(ushort4*)(C + row * (size_t)N + cb) = o;
            }
        }
    }
    if constexpr (EPI == 1) {
        #pragma unroll
        for (int ni = 0; ni < 4; ++ni)
            #pragma unroll
            for (int rg = 0; rg < 4; ++rg) {
                float s = cs[ni][rg];
                s += __shfl_xor(s, 1, 64);
                s += __shfl_xor(s, 2, 64);
                s += __shfl_xor(s, 4, 64);
                s += __shfl_xor(s, 8, 64);
                if (l16 == 0)
                    atomicAdd(&norm2[(bm >> 5) * 256 + bn * 128 + wn * 64 + ni * 16 + quad * 4 + rg], s);
            }
    }
    if constexpr (EPI == 4) {
        #pragma unroll
        for (int mi = 0; mi < 4; ++mi) {
            float s = rs[mi], q = rq[mi];
            s += __shfl_xor(s, 16, 64); s += __shfl_xor(s, 32, 64);
            q += __shfl_xor(q, 16, 64); q += __shfl_xor(q, 32, 64);
            if (quad == 0) {
                const size_t row = (size_t)bm * 128 + wm * 64 + mi * 16 + l16;
                atomicAdd(&rowstats[row * 2], s);
                atomicAdd(&rowstats[row * 2 + 1], q);
            }
        }
    }
}

// ---------------------------------------------------------------------------
// GEMM1 (unswapped, BK=32): [s|v] = x_bf @ [Wqk;Wv]^T + b, rope in epilogue
// ---------------------------------------------------------------------------
__global__ __launch_bounds__(256) void gemm_rope(
    const unsigned short* __restrict__ A,
    const unsigned short* __restrict__ Wsv,
    const float* __restrict__ bsv,
    const float* __restrict__ enc,
    unsigned short* __restrict__ wi)
{
    __shared__ alignas(16) unsigned short As[128 * 32];
    __shared__ alignas(16) unsigned short Ss[128 * 32];
    __shared__ alignas(16) unsigned short Vs[128 * 32];

    const int t = threadIdx.x;
    const int bn = blockIdx.x;
    const int bm = blockIdx.y;
    const int lane = t & 63, wave = t >> 6;
    const int wm = wave >> 1, wn = wave & 1;
    const int quad = lane >> 4, l16 = lane & 15;
    const int rA = t >> 2, cA = (t & 3) * 8;

    floatx4 accs[4][4], accv[4][4];
    #pragma unroll
    for (int i = 0; i < 4; ++i)
        #pragma unroll
        for (int j = 0; j < 4; ++j) {
            accs[i][j] = (floatx4){0.f, 0.f, 0.f, 0.f};
            accv[i][j] = (floatx4){0.f, 0.f, 0.f, 0.f};
        }

    for (int k0 = 0; k0 < 256; k0 += 32) {
        #pragma unroll
        for (int hh = 0; hh < 2; ++hh) {
            const int r = rA + hh * 64;
            gll16(A + ((size_t)bm * 128 + r) * 256 + k0 + cA, &As[t * 8 + hh * 2048]);
            gll16(Wsv + (size_t)(bn * 128 + r) * 256 + k0 + cA, &Ss[t * 8 + hh * 2048]);
            gll16(Wsv + (size_t)(256 + bn * 128 + r) * 256 + k0 + cA, &Vs[t * 8 + hh * 2048]);
        }
        __syncthreads();

        short8 af[4], sf[4], vf[4];
        #pragma unroll
        for (int i = 0; i < 4; ++i) {
            af[i] = *(const short8*)(&As[(wm * 64 + i * 16 + l16) * 32 + quad * 8]);
            sf[i] = *(const short8*)(&Ss[(wn * 64 + i * 16 + l16) * 32 + quad * 8]);
            vf[i] = *(const short8*)(&Vs[(wn * 64 + i * 16 + l16) * 32 + quad * 8]);
        }
        #pragma unroll
        for (int mi = 0; mi < 4; ++mi)
            #pragma unroll
            for (int ni = 0; ni < 4; ++ni) {
                accs[mi][ni] = __builtin_amdgcn_mfma_f32_16x16x32_bf16(af[mi], sf[ni], accs[mi][ni], 0, 0, 0);
                accv[mi][ni] = __builtin_amdgcn_mfma_f32_16x16x32_bf16(af[mi], vf[ni], accv[mi][ni], 0, 0, 0);
            }
        __syncthreads();
    }

    #pragma unroll
    for (int ni = 0; ni < 4; ++ni) {
        const int cg = bn * 128 + wn * 64 + ni * 16 + l16;
        const int d = cg & 63;
        const float sign = (d & 1) ? 1.f : -1.f;
        const float bs = bsv[cg], bv = bsv[256 + cg];
        #pragma unroll
        for (int mi = 0; mi < 4; ++mi) {
            const int rowb = bm * 128 + wm * 64 + mi * 16 + quad * 4;
            #pragma unroll
            for (int rg = 0; rg < 4; ++rg) {
                const size_t row = (size_t)rowb + rg;
                const float sv = accs[mi][ni][rg] + bs;
                const float vv = accv[mi][ni][rg] + bv;
                const float partner = __shfl_xor(sv, 1, 64);
                const size_t eo = row * 64 + d;
                const float e0 = enc[eo];
                const float e1 = enc[4194304 + eo];
                const float r = sv * e0 + sign * partner * e1;
                wi[row * 256 + cg] = f2bf((r + vv) * (1.f / 3.f));
            }
        }
    }
}

// ---------------------------------------------------------------------------
// single prep kernel: converts + fused weights + zeroing
// ---------------------------------------------------------------------------
__device__ __forceinline__ void conv8(const float* src, unsigned short* dst, int i) {
    const float4 f0 = *(const float4*)(src + (size_t)i * 8);
    const float4 f1 = *(const float4*)(src + (size_t)i * 8 + 4);
    short8 sv;
    sv[0] = (short)f2bf(f0.x); sv[1] = (short)f2bf(f0.y);
    sv[2] = (short)f2bf(f0.z); sv[3] = (short)f2bf(f0.w);
    sv[4] = (short)f2bf(f1.x); sv[5] = (short)f2bf(f1.y);
    sv[6] = (short)f2bf(f1.z); sv[7] = (short)f2bf(f1.w);
    *(short8*)(dst + (size_t)i * 8) = sv;
}

__global__ __launch_bounds__(256) void prep_all(
    const float* __restrict__ x, const float* __restrict__ Wqkv,
    const float* __restrict__ bqkv, const float* __restrict__ tssa_w,
    const float* __restrict__ op_w, const float* __restrict__ to_w,
    const float* __restrict__ to_b, const float* __restrict__ op_b,
    const float* __restrict__ f1w, const float* __restrict__ f2w,
    unsigned short* __restrict__ x_bf, unsigned short* __restrict__ Wsv,
    float* __restrict__ bsv, unsigned short* __restrict__ tssa_bf,
    unsigned short* __restrict__ Wf, float* __restrict__ bfb,
    unsigned short* __restrict__ ffn1_bf, unsigned short* __restrict__ ffn2_bf,
    float* __restrict__ zbase, float* __restrict__ rowstats)
{
    const int blk = blockIdx.x, tt = threadIdx.x;
    if (blk < 8192) {
        conv8(x, x_bf, blk * 256 + tt);
    } else if (blk < 8704) {
        const int r = blk - 8192, c = tt;
        const int cd = r & 255;
        const int h = cd >> 6, dd = cd & 63;
        const int base = h * 192 + dd * 3;
        if (r < 256) {
            Wsv[r * 256 + c] = f2bf(Wqkv[(base + 0) * 256 + c] + Wqkv[(base + 1) * 256 + c]);
            if (c == 0) bsv[r] = bqkv[base] + bqkv[base + 1];
        } else {
            Wsv[r * 256 + c] = f2bf(Wqkv[(base + 2) * 256 + c]);
            if (c == 0) bsv[r] = bqkv[base + 2];
        }
    } else if (blk < 8960) {
        const int i = blk - 8704;
        float s = 0.f;
        for (int k = 0; k < 256; ++k) s += op_w[i * 256 + k] * to_w[k * 256 + tt];
        Wf[i * 256 + tt] = f2bf(s);
    } else if (blk == 8960) {
        float s = op_b[tt];
        for (int k = 0; k < 256; ++k) s += op_w[tt * 256 + k] * to_b[k];
        bfb[tt] = s;
    } else if (blk < 8993) {
        conv8(tssa_w, tssa_bf, (blk - 8961) * 256 + tt);
    } else if (blk < 9121) {
        conv8(f1w, ffn1_bf, (blk - 8993) * 256 + tt);
    } else if (blk < 9185) {
        conv8(f2w, ffn2_bf, (blk - 9121) * 256 + tt);
    } else {
        const int i = (blk - 9185) * 256 + tt;
        if (i < 4288) zbase[i] = 0.f;
        else if (i < 135360) rowstats[i - 4288] = 0.f;
    }
}

// ---------------------------------------------------------------------------
// per-row softmax over heads + S/T accumulation
// ---------------------------------------------------------------------------
__global__ __launch_bounds__(256) void pi_kernel(const unsigned short* __restrict__ w,
                                                 const float* __restrict__ norm2,
                                                 const float* __restrict__ temp,
                                                 float* __restrict__ Pi,
                                                 float* __restrict__ S,
                                                 float* __restrict__ T) {
    const int t = threadIdx.x;
    const int i = t & 15;
    const int lr = t >> 4;
    const size_t r = (size_t)blockIdx.x * 16 + lr;
    const int b = (int)(r >> 12);
    const unsigned short* wrow = w + r * 256;
    const float* n2row = norm2 + b * 256;
    float raw[4], nrm[4];
    #pragma unroll
    for (int h = 0; h < 4; ++h) {
        const ushort4 wv = *(const ushort4*)(wrow + h * 64 + i * 4);
        const float w0 = bf2f(wv.x), w1 = bf2f(wv.y), w2 = bf2f(wv.z), w3 = bf2f(wv.w);
        const float4 n2 = *(const float4*)(n2row + h * 64 + i * 4);
        const float s0 = w0 * w0, s1 = w1 * w1, s2 = w2 * w2, s3 = w3 * w3;
        raw[h] = s0 + s1 + s2 + s3;
        nrm[h] = s0 / fmaxf(n2.x, 1e-24f) + s1 / fmaxf(n2.y, 1e-24f)
               + s2 / fmaxf(n2.z, 1e-24f) + s3 / fmaxf(n2.w, 1e-24f);
    }
    #pragma unroll
    for (int off = 1; off < 16; off <<= 1) {
        #pragma unroll
        for (int h = 0; h < 4; ++h) {
            raw[h] += __shfl_xor(raw[h], off, 64);
            nrm[h] += __shfl_xor(nrm[h], off, 64);
        }
    }
    float sw[4], m = -1e30f;
    #pragma unroll
    for (int h = 0; h < 4; ++h) { sw[h] = nrm[h] * temp[h]; m = fmaxf(m, sw[h]); }
    float e[4], Z = 0.f;
    #pragma unroll
    for (int h = 0; h < 4; ++h) { e[h] = expf(sw[h] - m); Z += e[h]; }
    const float invZ = 1.f / Z;
    float pi[4];
    #pragma unroll
    for (int h = 0; h < 4; ++h) pi[h] = e[h] * invZ;
    if (i < 4) Pi[r * 4 + i] = pi[i];

    __shared__ float sS[16][4], sT[16][4];
    if (i == 0) {
        #pragma unroll
        for (int h = 0; h < 4; ++h) { sS[lr][h] = pi[h]; sT[lr][h] = pi[h] * raw[h]; }
    }
    __syncthreads();
    if (t < 4) {
        float as = 0.f, at = 0.f;
        for (int rr = 0; rr < 16; ++rr) { as += sS[rr][t]; at += sT[rr][t]; }
        atomicAdd(&S[b * 4 + t], as);
        atomicAdd(&T[b * 4 + t], at);
    }
}

__global__ void attn_kernel(const float* __restrict__ S, const float* __restrict__ T,
                            float* __restrict__ attn) {
    const int i = threadIdx.x;  // 64
    const float dots = T[i] / (S[i] + 1e-8f);
    attn[i] = 1.f / (1.f + dots);
}

// ---------------------------------------------------------------------------
extern "C" void kernel_launch(void* const* d_in, const int* in_sizes, int n_in,
                              void* d_out, int out_size, void* d_ws, size_t ws_size,
                              hipStream_t stream) {
    (void)in_sizes; (void)n_in; (void)out_size; (void)ws_size;
    const float* x          = (const float*)d_in[0];
    const float* enc        = (const float*)d_in[1];
    const float* Wqkv_w     = (const float*)d_in[2];
    const float* Wqkv_b     = (const float*)d_in[3];
    const float* tssa_qkv_w = (const float*)d_in[4];
    const float* tssa_qkv_b = (const float*)d_in[5];
    const float* temp       = (const float*)d_in[6];
    const float* tssa_out_w = (const float*)d_in[7];
    const float* tssa_out_b = (const float*)d_in[8];
    const float* out_proj_w = (const float*)d_in[9];
    const float* out_proj_b = (const float*)d_in[10];
    const float* ffn1_w     = (const float*)d_in[11];
    const float* ffn1_b     = (const float*)d_in[12];
    const float* ln_g       = (const float*)d_in[13];
    const float* ln_b       = (const float*)d_in[14];
    const float* ffn2_w     = (const float*)d_in[15];
    const float* ffn2_b     = (const float*)d_in[16];
    float* outp = (float*)d_out;

    const int M = Bc * Nc;  // 65536

    // ws layout: [0,32M) x_bf | [32,64M) wi_bf / h1_bf lower | [64,96M) w_bf / h1 upper
    // [96,128M) msg_bf | [128M,..) fp32 stats then bf16 weights
    char* ws = (char*)d_ws;
    unsigned short* x_bf  = (unsigned short*)(ws);
    unsigned short* wi_bf = (unsigned short*)(ws + (size_t)(32 << 20));
    unsigned short* h1_bf = (unsigned short*)(ws + (size_t)(32 << 20));
    unsigned short* w_bf  = (unsigned short*)(ws + (size_t)(64 << 20));
    unsigned short* msg_bf= (unsigned short*)(ws + (size_t)(96 << 20));
    float* fb    = (float*)(ws + (size_t)(128 << 20));
    float* Pi    = fb;                 // 262144
    float* norm2 = Pi + 262144;        // 4096  <- zbase starts here
    float* Sb    = norm2 + 4096;       // 64
    float* Tb    = Sb + 64;            // 64
    float* attnb = Tb + 64;            // 64
    float* bsv   = attnb + 64;         // 512
    float* bfb   = bsv + 512;          // 256
    float* rowstats = bfb + 256;       // 131072 (float2 per row)
    unsigned short* Wsv_bf  = (unsigned short*)(rowstats + 131072);  // 512x256
    unsigned short* tssa_bf = Wsv_bf + 131072;                       // 256x256
    unsigned short* Wf_bf   = tssa_bf + 65536;                       // 256x256
    unsigned short* ffn1_bf = Wf_bf + 65536;                         // 512x512
    unsigned short* ffn2_bf = ffn1_bf + 262144;                      // 256x512

    // 1. all prep in one kernel
    prep_all<<<9714, 256, 0, stream>>>(
        x, Wqkv_w, Wqkv_b, tssa_qkv_w, out_proj_w, tssa_out_w, tssa_out_b,
        out_proj_b, ffn1_w, ffn2_w,
        x_bf, Wsv_bf, bsv, tssa_bf, Wf_bf, bfb, ffn1_bf, ffn2_bf,
        norm2, rowstats);

    // 2. G1: wi = rope-combine(x_bf @ [Wqk;Wv]^T + b)
    gemm_rope<<<dim3(2, M / 128), 256, 0, stream>>>(x_bf, Wsv_bf, bsv, enc, wi_bf);

    // 3. G2: w = wi @ tssa^T + b -> bf16, fused colsq -> norm2
    gemm_bf<1, unsigned short><<<dim3(2, M / 128), 256, 0, stream>>>(
        wi_bf, 256, wi_bf, 256, 256, tssa_bf, tssa_qkv_b,
        nullptr, nullptr, nullptr, nullptr, nullptr, nullptr,
        norm2, nullptr, w_bf, 256, 256);

    // 4/5. stats
    pi_kernel<<<4096, 256, 0, stream>>>(w_bf, norm2, temp, Pi, Sb, Tb);
    attn_kernel<<<1, 64, 0, stream>>>(Sb, Tb, attnb);

    // 6. G3: message = (-w*Pi*attn) @ Wf^T + bfb
    gemm_bf<2, unsigned short><<<dim3(2, M / 128), 256, 0, stream>>>(
        w_bf, 256, w_bf, 256, 256, Wf_bf, bfb,
        nullptr, Pi, attnb, nullptr, nullptr, nullptr,
        nullptr, nullptr, msg_bf, 256, 256);

    // 7. G4: h1 = [x_bf, msg] @ ffn1^T + b -> bf16, fused row sum/sumsq
    gemm_bf<4, unsigned short><<<dim3(4, M / 128), 256, 0, stream>>>(
        x_bf, 256, msg_bf, 256, 256, ffn1_bf, ffn1_b,
        nullptr, nullptr, nullptr, nullptr, nullptr, nullptr,
        nullptr, rowstats, h1_bf, 512, 512);

    // 8. G5: out = x + gelu(LN(h1)) @ ffn2^T + b  (LN+gelu in A-staging)
    gemm_bf<3, float><<<dim3(2, M / 128), 256, 0, stream>>>(
        h1_bf, 512, h1_bf, 512, 512, ffn2_bf, ffn2_b,
        x_bf, nullptr, nullptr, rowstats, ln_g, ln_b,
        nullptr, nullptr, outp, 256, 512);
}

// Round 5
// 456.748 us; speedup vs baseline: 1.5412x; 1.1209x over previous
//
#include <hip/hip_runtime.h>
#include <math.h>

#define Bc 16
#define Nc 4096

typedef __attribute__((ext_vector_type(8))) short short8;
typedef __attribute__((ext_vector_type(4))) float floatx4;

__device__ __forceinline__ unsigned short f2bf(float f) {
    union { float f; unsigned int u; } v; v.f = f;
    unsigned int u = v.u;
    return (unsigned short)((u + 0x7fffu + ((u >> 16) & 1u)) >> 16);
}
__device__ __forceinline__ float bf2f(unsigned short u) {
    union { unsigned int u; float f; } v; v.u = ((unsigned int)u) << 16;
    return v.f;
}

// async global->LDS 16B/lane; LDS dest must be wave-uniform base + lane*16
__device__ __forceinline__ void gll16(const unsigned short* g, unsigned short* l) {
    __builtin_amdgcn_global_load_lds(
        (const __attribute__((address_space(1))) void*)g,
        (__attribute__((address_space(3))) void*)l,
        16, 0, 0);
}

// ---------------------------------------------------------------------------
// Swapped-operand bf16 GEMM, 512 threads, tile 128(M)x256(N), BK=64.
// mfma(wf, af, acc): D col = quad*4+rg (vector stores), D row = l16.
// XOR-granule LDS swizzle (bank-conflict-free, gll16-compatible).
// EPI 1: + column sum-of-squares -> norm2        (G2)
// EPI 2: A staged with scale -Pi*attn (VALU)     (G3)
// EPI 3: + bf16 residual, fp32 out               (G5)
// EPI 4: + per-row sum/sumsq -> rowstats         (G4)
// ---------------------------------------------------------------------------
template <int EPI, typename TOUT>
__global__ __launch_bounds__(512) void gemm_bf(
    const unsigned short* __restrict__ A0, int lda0,
    const unsigned short* __restrict__ A1, int lda1, int K0,
    const unsigned short* __restrict__ W,
    const float* __restrict__ bias,
    const unsigned short* __restrict__ resid_bf,   // EPI3
    const float* __restrict__ Pi,                  // EPI2
    const float* __restrict__ attnb,               // EPI2
    float* __restrict__ norm2,                     // EPI1
    float* __restrict__ rowstats,                  // EPI4
    TOUT* __restrict__ C, int N, int K)
{
    __shared__ alignas(16) unsigned short As[128 * 64];
    __shared__ alignas(16) unsigned short Bs[256 * 64];

    const int t = threadIdx.x;
    const int bn = blockIdx.x, bm = blockIdx.y;
    const int lane = t & 63, wave = t >> 6;          // 8 waves
    const int wm = wave >> 2, wn = wave & 3;         // 2 x 4
    const int quad = lane >> 4, l16 = lane & 15;
    const int rt = t >> 3, st = t & 7;               // rt 0..63

    floatx4 acc[4][4];
    #pragma unroll
    for (int i = 0; i < 4; ++i)
        #pragma unroll
        for (int j = 0; j < 4; ++j)
            acc[i][j] = (floatx4){0.f, 0.f, 0.f, 0.f};

    for (int k0 = 0; k0 < K; k0 += 64) {
        // A tile: 128 rows x 64
        #pragma unroll
        for (int hh = 0; hh < 2; ++hh) {
            const int row = hh * 64 + rt;
            const int col = k0 + (st ^ (row & 7)) * 8;
            unsigned short* ldsa = As + row * 64 + st * 8;
            const size_t grow = (size_t)bm * 128 + row;
            if constexpr (EPI == 2) {
                const int b = (int)(grow >> 12);
                const int hd = col >> 6;
                const float sc = -Pi[grow * 4 + hd] * attnb[b * 4 + hd];
                const short8 a = *(const short8*)(A0 + grow * (size_t)lda0 + col);
                short8 o;
                #pragma unroll
                for (int j = 0; j < 8; ++j) o[j] = (short)f2bf(bf2f((unsigned short)a[j]) * sc);
                *(short8*)ldsa = o;
            } else {
                const unsigned short* src = (col < K0)
                    ? (A0 + grow * (size_t)lda0 + col)
                    : (A1 + grow * (size_t)lda1 + (col - K0));
                gll16(src, ldsa);
            }
        }
        // W tile: 256 rows x 64
        #pragma unroll
        for (int hh = 0; hh < 4; ++hh) {
            const int row = hh * 64 + rt;
            const int col = k0 + (st ^ (row & 7)) * 8;
            gll16(W + ((size_t)bn * 256 + row) * (size_t)K + col, Bs + row * 64 + st * 8);
        }
        __syncthreads();
        #pragma unroll
        for (int kk = 0; kk < 2; ++kk) {
            short8 af[4], wf[4];
            #pragma unroll
            for (int i = 0; i < 4; ++i) {
                const int ra = wm * 64 + i * 16 + l16;
                af[i] = *(const short8*)(As + ra * 64 + ((quad + kk * 4) ^ (ra & 7)) * 8);
                const int rw = wn * 64 + i * 16 + l16;
                wf[i] = *(const short8*)(Bs + rw * 64 + ((quad + kk * 4) ^ (rw & 7)) * 8);
            }
            #pragma unroll
            for (int mi = 0; mi < 4; ++mi)
                #pragma unroll
                for (int ni = 0; ni < 4; ++ni)
                    acc[mi][ni] = __builtin_amdgcn_mfma_f32_16x16x32_bf16(
                        wf[ni], af[mi], acc[mi][ni], 0, 0, 0);
        }
        __syncthreads();
    }

    // epilogue: row = bm*128+wm*64+mi*16+l16; col = bn*256+wn*64+ni*16+quad*4+rg
    float rs[4], rq[4];
    if constexpr (EPI == 4) {
        #pragma unroll
        for (int m = 0; m < 4; ++m) { rs[m] = 0.f; rq[m] = 0.f; }
    }

    #pragma unroll
    for (int mi = 0; mi < 4; ++mi) {
        const size_t row = (size_t)bm * 128 + wm * 64 + mi * 16 + l16;
        #pragma unroll
        for (int ni = 0; ni < 4; ++ni) {
            const int cb = bn * 256 + wn * 64 + ni * 16 + quad * 4;
            const float4 b4 = *(const float4*)(bias + cb);
            float v[4] = {acc[mi][ni][0] + b4.x, acc[mi][ni][1] + b4.y,
                          acc[mi][ni][2] + b4.z, acc[mi][ni][3] + b4.w};
            if constexpr (EPI == 3) {
                const ushort4 xr = *(const ushort4*)(resid_bf + row * (size_t)N + cb);
                v[0] += bf2f(xr.x); v[1] += bf2f(xr.y);
                v[2] += bf2f(xr.z); v[3] += bf2f(xr.w);
            }
            if constexpr (EPI == 4) {
                #pragma unroll
                for (int rg = 0; rg < 4; ++rg) { rs[mi] += v[rg]; rq[mi] += v[rg] * v[rg]; }
            }
            if constexpr (EPI == 1) {
                float cs[4];
                #pragma unroll
                for (int rg = 0; rg < 4; ++rg) cs[rg] = v[rg] * v[rg];
                #pragma unroll
                for (int rg = 0; rg < 4; ++rg) {
                    float s = cs[rg];
                    s += __shfl_xor(s, 1, 64);
                    s += __shfl_xor(s, 2, 64);
                    s += __shfl_xor(s, 4, 64);
                    s += __shfl_xor(s, 8, 64);
                    if (l16 == 0) atomicAdd(&norm2[(bm >> 5) * 256 + cb + rg], s);
                }
            }
            if constexpr (__is_same(TOUT, float)) {
                float4 o; o.x = v[0]; o.y = v[1]; o.z = v[2]; o.w = v[3];
                *(float4*)(C + row * (size_t)N + cb) = o;
            } else {
                ushort4 o;
                o.x = f2bf(v[0]); o.y = f2bf(v[1]); o.z = f2bf(v[2]); o.w = f2bf(v[3]);
                *(ushort4*)(C + row * (size_t)N + cb) = o;
            }
        }
    }
    if constexpr (EPI == 4) {
        #pragma unroll
        for (int mi = 0; mi < 4; ++mi) {
            float s = rs[mi], q = rq[mi];
            s += __shfl_xor(s, 16, 64); s += __shfl_xor(s, 32, 64);
            q += __shfl_xor(q, 16, 64); q += __shfl_xor(q, 32, 64);
            if (quad == 0) {
                const size_t row = (size_t)bm * 128 + wm * 64 + mi * 16 + l16;
                atomicAdd(&rowstats[row * 2], s);
                atomicAdd(&rowstats[row * 2 + 1], q);
            }
        }
    }
}

// ---------------------------------------------------------------------------
// G1 (swapped, 256 threads, 128x128 tile, BK=64): dual-acc s/v GEMM with
// in-lane rope epilogue. wi = ((q+k)*e0 + rot(q+k)*e1 + v)/3.
// ---------------------------------------------------------------------------
__global__ __launch_bounds__(256) void gemm_rope(
    const unsigned short* __restrict__ A,    // x_bf
    const unsigned short* __restrict__ Wsv,  // 512x256: rows 0-255 s, 256-511 v
    const float* __restrict__ bsv,           // 512
    const float* __restrict__ enc,
    unsigned short* __restrict__ wi)
{
    __shared__ alignas(16) unsigned short As[128 * 64];
    __shared__ alignas(16) unsigned short Ss[128 * 64];
    __shared__ alignas(16) unsigned short Vs[128 * 64];

    const int t = threadIdx.x;
    const int bn = blockIdx.x, bm = blockIdx.y;
    const int lane = t & 63, wave = t >> 6;
    const int wm = wave >> 1, wn = wave & 1;
    const int quad = lane >> 4, l16 = lane & 15;
    const int rt = t >> 3, st = t & 7;   // rt 0..31

    floatx4 accs[4][4], accv[4][4];
    #pragma unroll
    for (int i = 0; i < 4; ++i)
        #pragma unroll
        for (int j = 0; j < 4; ++j) {
            accs[i][j] = (floatx4){0.f, 0.f, 0.f, 0.f};
            accv[i][j] = (floatx4){0.f, 0.f, 0.f, 0.f};
        }

    for (int k0 = 0; k0 < 256; k0 += 64) {
        #pragma unroll
        for (int hh = 0; hh < 4; ++hh) {
            const int row = hh * 32 + rt;
            const int col = k0 + (st ^ (row & 7)) * 8;
            gll16(A + ((size_t)bm * 128 + row) * 256 + col, As + row * 64 + st * 8);
            gll16(Wsv + (size_t)(bn * 128 + row) * 256 + col, Ss + row * 64 + st * 8);
            gll16(Wsv + (size_t)(256 + bn * 128 + row) * 256 + col, Vs + row * 64 + st * 8);
        }
        __syncthreads();
        #pragma unroll
        for (int kk = 0; kk < 2; ++kk) {
            short8 af[4], sf[4], vf[4];
            #pragma unroll
            for (int i = 0; i < 4; ++i) {
                const int ra = wm * 64 + i * 16 + l16;
                af[i] = *(const short8*)(As + ra * 64 + ((quad + kk * 4) ^ (ra & 7)) * 8);
                const int rw = wn * 64 + i * 16 + l16;
                sf[i] = *(const short8*)(Ss + rw * 64 + ((quad + kk * 4) ^ (rw & 7)) * 8);
                vf[i] = *(const short8*)(Vs + rw * 64 + ((quad + kk * 4) ^ (rw & 7)) * 8);
            }
            #pragma unroll
            for (int mi = 0; mi < 4; ++mi)
                #pragma unroll
                for (int ni = 0; ni < 4; ++ni) {
                    accs[mi][ni] = __builtin_amdgcn_mfma_f32_16x16x32_bf16(sf[ni], af[mi], accs[mi][ni], 0, 0, 0);
                    accv[mi][ni] = __builtin_amdgcn_mfma_f32_16x16x32_bf16(vf[ni], af[mi], accv[mi][ni], 0, 0, 0);
                }
        }
        __syncthreads();
    }

    // epilogue: row = bm*128+wm*64+mi*16+l16; cols cb..cb+3 (pairs in-lane)
    #pragma unroll
    for (int mi = 0; mi < 4; ++mi) {
        const size_t row = (size_t)bm * 128 + wm * 64 + mi * 16 + l16;
        #pragma unroll
        for (int ni = 0; ni < 4; ++ni) {
            const int cb = bn * 128 + wn * 64 + ni * 16 + quad * 4;
            const int d = cb & 63;
            const float s0 = accs[mi][ni][0] + bsv[cb];
            const float s1 = accs[mi][ni][1] + bsv[cb + 1];
            const float s2 = accs[mi][ni][2] + bsv[cb + 2];
            const float s3 = accs[mi][ni][3] + bsv[cb + 3];
            const float v0 = accv[mi][ni][0] + bsv[256 + cb];
            const float v1 = accv[mi][ni][1] + bsv[256 + cb + 1];
            const float v2 = accv[mi][ni][2] + bsv[256 + cb + 2];
            const float v3 = accv[mi][ni][3] + bsv[256 + cb + 3];
            const float4 e0q = *(const float4*)(enc + row * 64 + d);
            const float4 e1q = *(const float4*)(enc + 4194304 + row * 64 + d);
            const float r0 = s0 * e0q.x - s1 * e1q.x;
            const float r1 = s1 * e0q.y + s0 * e1q.y;
            const float r2 = s2 * e0q.z - s3 * e1q.z;
            const float r3 = s3 * e0q.w + s2 * e1q.w;
            ushort4 o;
            o.x = f2bf((r0 + v0) * (1.f / 3.f));
            o.y = f2bf((r1 + v1) * (1.f / 3.f));
            o.z = f2bf((r2 + v2) * (1.f / 3.f));
            o.w = f2bf((r3 + v3) * (1.f / 3.f));
            *(ushort4*)(wi + row * 256 + cb) = o;
        }
    }
}

// ---------------------------------------------------------------------------
// LN(512)+exact gelu streaming pass using precomputed rowstats (no reduction)
// ---------------------------------------------------------------------------
__global__ __launch_bounds__(256) void lngelu_kernel(unsigned short* __restrict__ h1,
                                                     const float* __restrict__ rowstats,
                                                     const float* __restrict__ g,
                                                     const float* __restrict__ bb) {
    const size_t gid = (size_t)blockIdx.x * 256 + threadIdx.x;
    const size_t row = gid >> 6;
    const int col = (int)(gid & 63) * 8;
    const float2 stv = *(const float2*)(rowstats + row * 2);
    const float mean = stv.x * (1.f / 512.f);
    const float var = stv.y * (1.f / 512.f) - mean * mean;
    const float rstd = rsqrtf(var + 1e-5f);
    unsigned short* p = h1 + row * 512 + col;
    const short8 hv = *(const short8*)p;
    const float4 g0 = *(const float4*)(g + col);
    const float4 g1 = *(const float4*)(g + col + 4);
    const float4 b0 = *(const float4*)(bb + col);
    const float4 b1 = *(const float4*)(bb + col + 4);
    const float vg[8] = {g0.x, g0.y, g0.z, g0.w, g1.x, g1.y, g1.z, g1.w};
    const float vb[8] = {b0.x, b0.y, b0.z, b0.w, b1.x, b1.y, b1.z, b1.w};
    short8 ov;
    #pragma unroll
    for (int k = 0; k < 8; ++k) {
        const float ln = (bf2f((unsigned short)hv[k]) - mean) * rstd * vg[k] + vb[k];
        ov[k] = (short)f2bf(0.5f * ln * (1.f + erff(ln * 0.70710678118654752f)));
    }
    *(short8*)p = ov;
}

// ---------------------------------------------------------------------------
// single prep kernel: converts + fused weights + zeroing
// ---------------------------------------------------------------------------
__device__ __forceinline__ void conv8(const float* src, unsigned short* dst, int i) {
    const float4 f0 = *(const float4*)(src + (size_t)i * 8);
    const float4 f1 = *(const float4*)(src + (size_t)i * 8 + 4);
    short8 sv;
    sv[0] = (short)f2bf(f0.x); sv[1] = (short)f2bf(f0.y);
    sv[2] = (short)f2bf(f0.z); sv[3] = (short)f2bf(f0.w);
    sv[4] = (short)f2bf(f1.x); sv[5] = (short)f2bf(f1.y);
    sv[6] = (short)f2bf(f1.z); sv[7] = (short)f2bf(f1.w);
    *(short8*)(dst + (size_t)i * 8) = sv;
}

__global__ __launch_bounds__(256) void prep_all(
    const float* __restrict__ x, const float* __restrict__ Wqkv,
    const float* __restrict__ bqkv, const float* __restrict__ tssa_w,
    const float* __restrict__ op_w, const float* __restrict__ to_w,
    const float* __restrict__ to_b, const float* __restrict__ op_b,
    const float* __restrict__ f1w, const float* __restrict__ f2w,
    unsigned short* __restrict__ x_bf, unsigned short* __restrict__ Wsv,
    float* __restrict__ bsv, unsigned short* __restrict__ tssa_bf,
    unsigned short* __restrict__ Wf, float* __restrict__ bfb,
    unsigned short* __restrict__ ffn1_bf, unsigned short* __restrict__ ffn2_bf,
    float* __restrict__ zbase, float* __restrict__ rowstats)
{
    const int blk = blockIdx.x, tt = threadIdx.x;
    if (blk < 8192) {
        conv8(x, x_bf, blk * 256 + tt);
    } else if (blk < 8704) {
        const int r = blk - 8192, c = tt;
        const int cd = r & 255;
        const int h = cd >> 6, dd = cd & 63;
        const int base = h * 192 + dd * 3;
        if (r < 256) {
            Wsv[r * 256 + c] = f2bf(Wqkv[(base + 0) * 256 + c] + Wqkv[(base + 1) * 256 + c]);
            if (c == 0) bsv[r] = bqkv[base] + bqkv[base + 1];
        } else {
            Wsv[r * 256 + c] = f2bf(Wqkv[(base + 2) * 256 + c]);
            if (c == 0) bsv[r] = bqkv[base + 2];
        }
    } else if (blk < 8960) {
        const int i = blk - 8704;
        float s = 0.f;
        for (int k = 0; k < 256; ++k) s += op_w[i * 256 + k] * to_w[k * 256 + tt];
        Wf[i * 256 + tt] = f2bf(s);
    } else if (blk == 8960) {
        float s = op_b[tt];
        for (int k = 0; k < 256; ++k) s += op_w[tt * 256 + k] * to_b[k];
        bfb[tt] = s;
    } else if (blk < 8993) {
        conv8(tssa_w, tssa_bf, (blk - 8961) * 256 + tt);
    } else if (blk < 9121) {
        conv8(f1w, ffn1_bf, (blk - 8993) * 256 + tt);
    } else if (blk < 9185) {
        conv8(f2w, ffn2_bf, (blk - 9121) * 256 + tt);
    } else {
        const int i = (blk - 9185) * 256 + tt;
        if (i < 4288) zbase[i] = 0.f;
        else if (i < 135360) rowstats[i - 4288] = 0.f;
    }
}

// ---------------------------------------------------------------------------
// per-row softmax over heads + S/T accumulation
// ---------------------------------------------------------------------------
__global__ __launch_bounds__(256) void pi_kernel(const unsigned short* __restrict__ w,
                                                 const float* __restrict__ norm2,
                                                 const float* __restrict__ temp,
                                                 float* __restrict__ Pi,
                                                 float* __restrict__ S,
                                                 float* __restrict__ T) {
    const int t = threadIdx.x;
    const int i = t & 15;
    const int lr = t >> 4;
    const size_t r = (size_t)blockIdx.x * 16 + lr;
    const int b = (int)(r >> 12);
    const unsigned short* wrow = w + r * 256;
    const float* n2row = norm2 + b * 256;
    float raw[4], nrm[4];
    #pragma unroll
    for (int h = 0; h < 4; ++h) {
        const ushort4 wv = *(const ushort4*)(wrow + h * 64 + i * 4);
        const float w0 = bf2f(wv.x), w1 = bf2f(wv.y), w2 = bf2f(wv.z), w3 = bf2f(wv.w);
        const float4 n2 = *(const float4*)(n2row + h * 64 + i * 4);
        const float s0 = w0 * w0, s1 = w1 * w1, s2 = w2 * w2, s3 = w3 * w3;
        raw[h] = s0 + s1 + s2 + s3;
        nrm[h] = s0 / fmaxf(n2.x, 1e-24f) + s1 / fmaxf(n2.y, 1e-24f)
               + s2 / fmaxf(n2.z, 1e-24f) + s3 / fmaxf(n2.w, 1e-24f);
    }
    #pragma unroll
    for (int off = 1; off < 16; off <<= 1) {
        #pragma unroll
        for (int h = 0; h < 4; ++h) {
            raw[h] += __shfl_xor(raw[h], off, 64);
            nrm[h] += __shfl_xor(nrm[h], off, 64);
        }
    }
    float sw[4], m = -1e30f;
    #pragma unroll
    for (int h = 0; h < 4; ++h) { sw[h] = nrm[h] * temp[h]; m = fmaxf(m, sw[h]); }
    float e[4], Z = 0.f;
    #pragma unroll
    for (int h = 0; h < 4; ++h) { e[h] = expf(sw[h] - m); Z += e[h]; }
    const float invZ = 1.f / Z;
    float pi[4];
    #pragma unroll
    for (int h = 0; h < 4; ++h) pi[h] = e[h] * invZ;
    if (i < 4) Pi[r * 4 + i] = pi[i];

    __shared__ float sS[16][4], sT[16][4];
    if (i == 0) {
        #pragma unroll
        for (int h = 0; h < 4; ++h) { sS[lr][h] = pi[h]; sT[lr][h] = pi[h] * raw[h]; }
    }
    __syncthreads();
    if (t < 4) {
        float as = 0.f, at = 0.f;
        for (int rr = 0; rr < 16; ++rr) { as += sS[rr][t]; at += sT[rr][t]; }
        atomicAdd(&S[b * 4 + t], as);
        atomicAdd(&T[b * 4 + t], at);
    }
}

__global__ void attn_kernel(const float* __restrict__ S, const float* __restrict__ T,
                            float* __restrict__ attn) {
    const int i = threadIdx.x;  // 64
    const float dots = T[i] / (S[i] + 1e-8f);
    attn[i] = 1.f / (1.f + dots);
}

// ---------------------------------------------------------------------------
extern "C" void kernel_launch(void* const* d_in, const int* in_sizes, int n_in,
                              void* d_out, int out_size, void* d_ws, size_t ws_size,
                              hipStream_t stream) {
    (void)in_sizes; (void)n_in; (void)out_size; (void)ws_size;
    const float* x          = (const float*)d_in[0];
    const float* enc        = (const float*)d_in[1];
    const float* Wqkv_w     = (const float*)d_in[2];
    const float* Wqkv_b     = (const float*)d_in[3];
    const float* tssa_qkv_w = (const float*)d_in[4];
    const float* tssa_qkv_b = (const float*)d_in[5];
    const float* temp       = (const float*)d_in[6];
    const float* tssa_out_w = (const float*)d_in[7];
    const float* tssa_out_b = (const float*)d_in[8];
    const float* out_proj_w = (const float*)d_in[9];
    const float* out_proj_b = (const float*)d_in[10];
    const float* ffn1_w     = (const float*)d_in[11];
    const float* ffn1_b     = (const float*)d_in[12];
    const float* ln_g       = (const float*)d_in[13];
    const float* ln_b       = (const float*)d_in[14];
    const float* ffn2_w     = (const float*)d_in[15];
    const float* ffn2_b     = (const float*)d_in[16];
    float* outp = (float*)d_out;

    const int M = Bc * Nc;  // 65536

    char* ws = (char*)d_ws;
    unsigned short* x_bf  = (unsigned short*)(ws);
    unsigned short* wi_bf = (unsigned short*)(ws + (size_t)(32 << 20));
    unsigned short* h1_bf = (unsigned short*)(ws + (size_t)(32 << 20));
    unsigned short* w_bf  = (unsigned short*)(ws + (size_t)(64 << 20));
    unsigned short* msg_bf= (unsigned short*)(ws + (size_t)(96 << 20));
    float* fb    = (float*)(ws + (size_t)(128 << 20));
    float* Pi    = fb;                 // 262144
    float* norm2 = Pi + 262144;        // 4096  <- zero base
    float* Sb    = norm2 + 4096;       // 64
    float* Tb    = Sb + 64;            // 64
    float* attnb = Tb + 64;            // 64
    float* bsv   = attnb + 64;         // 512
    float* bfb   = bsv + 512;          // 256
    float* rowstats = bfb + 256;       // 131072
    unsigned short* Wsv_bf  = (unsigned short*)(rowstats + 131072);
    unsigned short* tssa_bf = Wsv_bf + 131072;
    unsigned short* Wf_bf   = tssa_bf + 65536;
    unsigned short* ffn1_bf = Wf_bf + 65536;
    unsigned short* ffn2_bf = ffn1_bf + 262144;

    // 1. prep
    prep_all<<<9714, 256, 0, stream>>>(
        x, Wqkv_w, Wqkv_b, tssa_qkv_w, out_proj_w, tssa_out_w, tssa_out_b,
        out_proj_b, ffn1_w, ffn2_w,
        x_bf, Wsv_bf, bsv, tssa_bf, Wf_bf, bfb, ffn1_bf, ffn2_bf,
        norm2, rowstats);

    // 2. G1: wi = rope-combine(x_bf @ [Wqk;Wv]^T + b)
    gemm_rope<<<dim3(2, M / 128), 256, 0, stream>>>(x_bf, Wsv_bf, bsv, enc, wi_bf);

    // 3. G2: w = wi @ tssa^T + b -> bf16, fused colsq -> norm2
    gemm_bf<1, unsigned short><<<dim3(1, M / 128), 512, 0, stream>>>(
        wi_bf, 256, wi_bf, 256, 256, tssa_bf, tssa_qkv_b,
        nullptr, nullptr, nullptr, norm2, nullptr, w_bf, 256, 256);

    // 4/5. stats
    pi_kernel<<<4096, 256, 0, stream>>>(w_bf, norm2, temp, Pi, Sb, Tb);
    attn_kernel<<<1, 64, 0, stream>>>(Sb, Tb, attnb);

    // 6. G3: message = (-w*Pi*attn) @ Wf^T + bfb
    gemm_bf<2, unsigned short><<<dim3(1, M / 128), 512, 0, stream>>>(
        w_bf, 256, w_bf, 256, 256, Wf_bf, bfb,
        nullptr, Pi, attnb, nullptr, nullptr, msg_bf, 256, 256);

    // 7. G4: h1 = [x_bf, msg] @ ffn1^T + b -> bf16, fused row sum/sumsq
    gemm_bf<4, unsigned short><<<dim3(2, M / 128), 512, 0, stream>>>(
        x_bf, 256, msg_bf, 256, 256, ffn1_bf, ffn1_b,
        nullptr, nullptr, nullptr, nullptr, rowstats, h1_bf, 512, 512);

    // 8. LN+gelu streaming (rowstats precomputed)
    lngelu_kernel<<<16384, 256, 0, stream>>>(h1_bf, rowstats, ln_g, ln_b);

    // 9. G5: out = x + gelu(LN(h1)) @ ffn2^T + b (fp32 out, bf16 residual)
    gemm_bf<3, float><<<dim3(1, M / 128), 512, 0, stream>>>(
        h1_bf, 512, h1_bf, 512, 512, ffn2_bf, ffn2_b,
        x_bf, nullptr, nullptr, nullptr, nullptr, outp, 256, 512);
}